// Round 4
// baseline (39592.667 us; speedup 1.0000x reference)
//
#include <hip/hip_runtime.h>
#include <hip/hip_bf16.h>
#include <math.h>

#define B_ 64
#define T_ 512
#define I_ 512
#define H_ 1024

// ---------------------------------------------------------------------------
// C[M,N] = A[M,K] @ Bt[N,K]^T + bias1[n] (+ bias2[n])
// A row r (r = t_local*64 + b) is at A + (r&63)*s1 + (r>>6)*s2.
//   K1 (gx): A = x + t0*I, s1 = T*I, s2 = I    -> reads x[b][t0+t][:]
//   K3 (xi): A = ys_chunk, s1 = H,   s2 = B*H  -> reads ys[t][b][:]
// Tile 128x128, BK=8, 256 threads, 8x8 per-thread register block.
// ---------------------------------------------------------------------------
__global__ __launch_bounds__(256) void gemm_bt_bias(
    const float* __restrict__ A, const float* __restrict__ Bt,
    const float* __restrict__ bias1, const float* __restrict__ bias2,
    float* __restrict__ C, int N, int K, long s1, long s2)
{
  __shared__ float As[8][132];   // 132%32==4 -> per-row bank rotation
  __shared__ float Bs[8][132];
  const int t   = threadIdx.x;
  const int r0  = blockIdx.y * 128;
  const int n0  = blockIdx.x * 128;
  const int lm  = t >> 1;          // 0..127 load row
  const int lk4 = (t & 1) * 4;     // 0 or 4
  const int tm0 = (t >> 4) * 8;    // 0..120
  const int tn0 = (t & 15) * 8;    // 0..120

  float acc[8][8] = {};

  for (int k0 = 0; k0 < K; k0 += 8) {
    const int r = r0 + lm;
    const float4 a = *(const float4*)(A + (long)(r & 63) * s1 + (long)(r >> 6) * s2 + k0 + lk4);
    const float4 b = *(const float4*)(Bt + (long)(n0 + lm) * K + k0 + lk4);
    As[lk4 + 0][lm] = a.x; As[lk4 + 1][lm] = a.y; As[lk4 + 2][lm] = a.z; As[lk4 + 3][lm] = a.w;
    Bs[lk4 + 0][lm] = b.x; Bs[lk4 + 1][lm] = b.y; Bs[lk4 + 2][lm] = b.z; Bs[lk4 + 3][lm] = b.w;
    __syncthreads();
#pragma unroll
    for (int kk = 0; kk < 8; ++kk) {
      const float4 a0 = *(const float4*)&As[kk][tm0];
      const float4 a1 = *(const float4*)&As[kk][tm0 + 4];
      const float4 b0 = *(const float4*)&Bs[kk][tn0];
      const float4 b1 = *(const float4*)&Bs[kk][tn0 + 4];
      const float am[8] = {a0.x, a0.y, a0.z, a0.w, a1.x, a1.y, a1.z, a1.w};
      const float bn[8] = {b0.x, b0.y, b0.z, b0.w, b1.x, b1.y, b1.z, b1.w};
#pragma unroll
      for (int i = 0; i < 8; ++i)
#pragma unroll
        for (int j = 0; j < 8; ++j)
          acc[i][j] = fmaf(am[i], bn[j], acc[i][j]);
    }
    __syncthreads();
  }

  float bs[8];
#pragma unroll
  for (int j = 0; j < 8; ++j) {
    const int n = n0 + tn0 + j;
    bs[j] = bias1[n] + (bias2 ? bias2[n] : 0.f);
  }
#pragma unroll
  for (int i = 0; i < 8; ++i) {
    const long r = r0 + tm0 + i;
    const float4 v0 = make_float4(acc[i][0] + bs[0], acc[i][1] + bs[1],
                                  acc[i][2] + bs[2], acc[i][3] + bs[3]);
    const float4 v1 = make_float4(acc[i][4] + bs[4], acc[i][5] + bs[5],
                                  acc[i][6] + bs[6], acc[i][7] + bs[7]);
    *(float4*)(C + r * N + n0 + tn0)     = v0;
    *(float4*)(C + r * N + n0 + tn0 + 4) = v1;
  }
}

// ---------------------------------------------------------------------------
// Grid barrier: monotonic counter, one atomic per WG, sense-free. Scans are
// launched with hipLaunchCooperativeKernel so co-residency is GUARANTEED.
// Counter is never reset; targets keep growing across chunk launches.
// ---------------------------------------------------------------------------
__device__ __forceinline__ void grid_barrier(unsigned* cnt, unsigned target)
{
  __syncthreads();
  if (threadIdx.x == 0) {
    __threadfence();  // publish this WG's stores (agent scope)
    __hip_atomic_fetch_add(cnt, 1u, __ATOMIC_ACQ_REL, __HIP_MEMORY_SCOPE_AGENT);
    while (__hip_atomic_load(cnt, __ATOMIC_ACQUIRE, __HIP_MEMORY_SCOPE_AGENT) < target)
      __builtin_amdgcn_s_sleep(1);
    __threadfence();  // acquire others' stores
  }
  __syncthreads();
}

// lane-select without runtime array indexing (keeps values in VGPRs, rule #20)
__device__ __forceinline__ float sel4(float a, float b, float c, float d, int u)
{
  return (u & 2) ? ((u & 1) ? d : c) : ((u & 1) ? b : a);
}

// ---------------------------------------------------------------------------
// Persistent LSTM scan (cooperative). 256 WGs; WG j owns hidden units
// j*4..j*4+3. LDS: its 16 W_hh rows (4 gates x 4 units), each row stored as
// 4 quarters at stride 260 floats (quarter bases hit banks {0,4,8,12} ->
// conflict-free 4-lane-group b128 reads with 16-way broadcast).
// Thread (b = t>>2, u = t&3) computes PARTIAL dots over k-quarter
// [u*256, u*256+256) for ALL 16 (gate,unit) pairs -> h reads are 1KB/thread
// (no 4x redundancy through L1); 2-stage __shfl_xor combines the quarters.
// c carried in a register within a launch, in cbuf across chunk launches.
// h double-buffered in global; nsteps even so state always ends in hA.
// ---------------------------------------------------------------------------
__global__ __launch_bounds__(256) void lstm_scan(
    const float* __restrict__ W_hh, const float* __restrict__ gx,
    float* __restrict__ ys, float* __restrict__ hA, float* __restrict__ hB,
    float* __restrict__ cbuf, unsigned* __restrict__ cnt, int base, int nsteps)
{
  __shared__ float Wl[16][1040];   // row r = gate*4+unit; quarter q at q*260
  const int wg = blockIdx.x, t = threadIdx.x;
  {
    const int ru = t >> 4, l16 = t & 15;
    const int q = ru >> 2, uu = ru & 3;
    const float* src = W_hh + (long)(q * H_ + wg * 4 + uu) * H_;
#pragma unroll
    for (int j = 0; j < 16; ++j) {
      const int k = l16 * 4 + j * 64;
      *(float4*)&Wl[ru][(k >> 8) * 260 + (k & 255)] = *(const float4*)(src + k);
    }
  }
  __syncthreads();

  const int b = t >> 2, u = t & 3;
  const int unit = wg * 4 + u;
  float creg = cbuf[b * H_ + unit];

  for (int ls = 0; ls < nsteps; ++ls) {
    const float* hp = (ls & 1) ? hB : hA;
    float*       hn = (ls & 1) ? hA : hB;
    const float* hq = hp + b * H_ + u * 256;        // this lane's k-quarter
    const float* wq = &Wl[0][0] + u * 260;          // quarter base, row stride 1040

    float p[4][4] = {};  // p[gate][unit-in-group], all indices compile-time
#pragma unroll 2
    for (int k4 = 0; k4 < 64; ++k4) {
      const float4 hv = *(const float4*)(hq + k4 * 4);
#pragma unroll
      for (int r = 0; r < 16; ++r) {
        const float4 wv = *(const float4*)(wq + r * 1040 + k4 * 4);
        float& a = p[r >> 2][r & 3];
        a = fmaf(hv.x, wv.x, a); a = fmaf(hv.y, wv.y, a);
        a = fmaf(hv.z, wv.z, a); a = fmaf(hv.w, wv.w, a);
      }
    }
    // combine the 4 k-quarters (lanes 4b..4b+3)
#pragma unroll
    for (int q = 0; q < 4; ++q)
#pragma unroll
      for (int uu = 0; uu < 4; ++uu) {
        p[q][uu] += __shfl_xor(p[q][uu], 1, 64);
        p[q][uu] += __shfl_xor(p[q][uu], 2, 64);
      }
    const float* gp = gx + (long)ls * (B_ * 4 * H_) + b * (4 * H_);
    const float gi = sel4(p[0][0], p[0][1], p[0][2], p[0][3], u) + gp[unit];
    const float gf = sel4(p[1][0], p[1][1], p[1][2], p[1][3], u) + gp[H_ + unit];
    const float gg = sel4(p[2][0], p[2][1], p[2][2], p[2][3], u) + gp[2 * H_ + unit];
    const float go = sel4(p[3][0], p[3][1], p[3][2], p[3][3], u) + gp[3 * H_ + unit];
    const float si = 1.f / (1.f + __expf(-gi));
    const float sf = 1.f / (1.f + __expf(-gf));
    const float so = 1.f / (1.f + __expf(-go));
    const float tg = tanhf(gg);
    creg = sf * creg + si * tg;
    const float hv_ = so * tanhf(creg);
    hn[b * H_ + unit] = hv_;
    ys[(long)ls * (B_ * H_) + b * H_ + unit] = hv_;
    grid_barrier(cnt, (unsigned)(base + ls + 1) * 256u);
  }
  cbuf[b * H_ + unit] = creg;  // carry c to the next chunk launch
}

// ---------------------------------------------------------------------------
// Persistent liquid scan (cooperative). Same k-split decomposition; W_rec
// slice (4 rows, quarter-padded) in LDS. h = h + leak*(tanh(xi_t + h@W_rec^T
// + b_rec) - h). out written every chunk; final chunk's write is the answer.
// ---------------------------------------------------------------------------
__global__ __launch_bounds__(256) void liq_scan(
    const float* __restrict__ W_rec, const float* __restrict__ xi,
    const float* __restrict__ b_rec, const float* __restrict__ tau,
    float* __restrict__ hA, float* __restrict__ hB, float* __restrict__ out,
    unsigned* __restrict__ cnt, int base, int nsteps)
{
  __shared__ float Wl[4][1040];
  const int wg = blockIdx.x, t = threadIdx.x;
  {
    const int ru = t >> 6, c0 = (t & 63) * 4;
    const float* src = W_rec + (long)(wg * 4 + ru) * H_;
#pragma unroll
    for (int j = 0; j < 4; ++j)
      *(float4*)&Wl[ru][j * 260 + c0] = *(const float4*)(src + c0 + j * 256);
  }
  __syncthreads();

  const int b = t >> 2, u = t & 3;
  const int unit = wg * 4 + u;
  const float tc   = fminf(fmaxf(tau[unit], 0.1f), 5.0f);
  const float leak = 0.1f / tc;   // DT / clip(tau)
  const float br   = b_rec[unit];
  float hlast = 0.f;

  for (int ls = 0; ls < nsteps; ++ls) {
    const float* hp = (ls & 1) ? hB : hA;
    float*       hn = (ls & 1) ? hA : hB;
    const float* hrow = hp + b * H_;
    const float* hq = hrow + u * 256;
    const float* wq = &Wl[0][0] + u * 260;
    float p0 = 0.f, p1 = 0.f, p2 = 0.f, p3 = 0.f;
#pragma unroll 4
    for (int k4 = 0; k4 < 64; ++k4) {
      const float4 hv = *(const float4*)(hq + k4 * 4);
      const float4 w0 = *(const float4*)(wq + 0 * 1040 + k4 * 4);
      const float4 w1 = *(const float4*)(wq + 1 * 1040 + k4 * 4);
      const float4 w2 = *(const float4*)(wq + 2 * 1040 + k4 * 4);
      const float4 w3 = *(const float4*)(wq + 3 * 1040 + k4 * 4);
      p0 = fmaf(hv.x, w0.x, p0); p0 = fmaf(hv.y, w0.y, p0);
      p0 = fmaf(hv.z, w0.z, p0); p0 = fmaf(hv.w, w0.w, p0);
      p1 = fmaf(hv.x, w1.x, p1); p1 = fmaf(hv.y, w1.y, p1);
      p1 = fmaf(hv.z, w1.z, p1); p1 = fmaf(hv.w, w1.w, p1);
      p2 = fmaf(hv.x, w2.x, p2); p2 = fmaf(hv.y, w2.y, p2);
      p2 = fmaf(hv.z, w2.z, p2); p2 = fmaf(hv.w, w2.w, p2);
      p3 = fmaf(hv.x, w3.x, p3); p3 = fmaf(hv.y, w3.y, p3);
      p3 = fmaf(hv.w, w3.w, p3); p3 = fmaf(hv.z, w3.z, p3);
    }
    p0 += __shfl_xor(p0, 1, 64); p0 += __shfl_xor(p0, 2, 64);
    p1 += __shfl_xor(p1, 1, 64); p1 += __shfl_xor(p1, 2, 64);
    p2 += __shfl_xor(p2, 1, 64); p2 += __shfl_xor(p2, 2, 64);
    p3 += __shfl_xor(p3, 1, 64); p3 += __shfl_xor(p3, 2, 64);
    const float acc = sel4(p0, p1, p2, p3, u);
    const float hself = hrow[unit];
    const float act = tanhf(xi[(long)ls * (B_ * H_) + b * H_ + unit] + acc + br);
    const float hnew = hself + leak * (act - hself);
    hn[b * H_ + unit] = hnew;
    hlast = hnew;
    grid_barrier(cnt, (unsigned)(base + ls + 1) * 256u);
  }
  out[b * H_ + unit] = hlast;
}

// ---------------------------------------------------------------------------
extern "C" void kernel_launch(void* const* d_in, const int* in_sizes, int n_in,
                              void* d_out, int out_size, void* d_ws, size_t ws_size,
                              hipStream_t stream)
{
  (void)in_sizes; (void)n_in; (void)out_size;
  const float* x     = (const float*)d_in[0];
  const float* W_ih  = (const float*)d_in[1];
  const float* W_hh  = (const float*)d_in[2];
  const float* b_ih  = (const float*)d_in[3];
  const float* b_hh  = (const float*)d_in[4];
  const float* W_in  = (const float*)d_in[5];
  const float* b_in  = (const float*)d_in[6];
  const float* W_rec = (const float*)d_in[7];
  const float* b_rec = (const float*)d_in[8];
  const float* tau   = (const float*)d_in[9];

  const size_t HB   = (size_t)B_ * H_ * sizeof(float);  // 256 KiB
  const size_t TAIL = 5 * HB + 1024;                    // cbuf + hA,hB,hLA,hLB + counters

  // Largest chunk length (even, divides T_) whose buffers fit the workspace.
  int Tc = T_;
  while (Tc > 2) {
    const size_t need = (size_t)Tc * B_ * 4 * H_ * 4   // gx chunk (also reused as xi)
                      + (size_t)Tc * B_ * H_ * 4       // ys chunk
                      + TAIL;
    if (need <= ws_size) break;
    Tc >>= 1;
  }

  char* ws = (char*)d_ws;
  const size_t GXB = (size_t)Tc * B_ * 4 * H_ * sizeof(float);
  const size_t YSB = (size_t)Tc * B_ * H_ * sizeof(float);
  float* gx   = (float*)ws;              // [Tc][B][4H]; reused as xi [Tc][B][H]
  float* ys   = (float*)(ws + GXB);      // [Tc][B][H]
  char*  tail = ws + GXB + YSB;
  float* cbuf = (float*)(tail);
  float* hA   = (float*)(tail + 1 * HB);
  float* hB   = (float*)(tail + 2 * HB);
  float* hLA  = (float*)(tail + 3 * HB);
  float* hLB  = (float*)(tail + 4 * HB);
  unsigned* cntS = (unsigned*)(tail + 5 * HB);        // LSTM barrier counter
  unsigned* cntL = (unsigned*)(tail + 5 * HB + 256);  // liquid barrier counter
  float* outp = (float*)d_out;

  // zero c/h state + counters (ws is re-poisoned to 0xAA before every launch)
  hipMemsetAsync(tail, 0, TAIL, stream);

  const int nch = T_ / Tc;
  for (int k = 0; k < nch; ++k) {
    int t0 = k * Tc;
    int ns = Tc;

    // K1: gx[t][b][g] = x[b][t0+t][:] @ W_ih^T + b_ih + b_hh
    gemm_bt_bias<<<dim3(4 * H_ / 128, Tc * B_ / 128), 256, 0, stream>>>(
        x + (long)t0 * I_, W_ih, b_ih, b_hh, gx, 4 * H_, I_,
        (long)T_ * I_, (long)I_);

    // K2: sequential LSTM scan over this chunk -> ys[t][b][h]  (cooperative:
    // co-residency of all 256 WGs is guaranteed, barrier cannot deadlock)
    {
      void* args[] = {(void*)&W_hh, (void*)&gx, (void*)&ys, (void*)&hA,
                      (void*)&hB, (void*)&cbuf, (void*)&cntS, (void*)&t0, (void*)&ns};
      hipLaunchCooperativeKernel((void*)lstm_scan, dim3(256), dim3(256),
                                 args, 0, stream);
    }

    // K3: xi[t][b][h] = ys[t][b][:] @ W_in^T + b_in  (into dead gx buffer)
    gemm_bt_bias<<<dim3(H_ / 128, Tc * B_ / 128), 256, 0, stream>>>(
        ys, W_in, b_in, nullptr, gx, H_, H_, (long)H_, (long)(B_ * H_));

    // K4: sequential liquid scan; final chunk writes d_out [B][H]
    {
      void* args[] = {(void*)&W_rec, (void*)&gx, (void*)&b_rec, (void*)&tau,
                      (void*)&hLA, (void*)&hLB, (void*)&outp, (void*)&cntL,
                      (void*)&t0, (void*)&ns};
      hipLaunchCooperativeKernel((void*)liq_scan, dim3(256), dim3(256),
                                 args, 0, stream);
    }
  }
}